// Round 1
// baseline (24286.839 us; speedup 1.0000x reference)
//
#include <hip/hip_runtime.h>
#include <hip/hip_bf16.h>
#include <stdint.h>

typedef __attribute__((ext_vector_type(8))) short short8;
typedef __attribute__((ext_vector_type(4))) short short4v;
typedef __attribute__((ext_vector_type(4))) float f32x4;

#define T_STEPS 512
#define BATCH 64
#define HDIM 1024
#define IDIM 1024
#define MROWS (T_STEPS * BATCH)  // 32768

__device__ __forceinline__ unsigned short f2bf(float f) {
  unsigned int u = __float_as_uint(f);
  u += 0x7FFFu + ((u >> 16) & 1u);  // RNE
  return (unsigned short)(u >> 16);
}

// ---------------- transpose + convert: dst[n][k] = bf16(src[k][n]), 1024x1024
__global__ __launch_bounds__(256) void transpose_cvt(const float* __restrict__ src,
                                                     unsigned short* __restrict__ dst) {
  __shared__ unsigned short tile[32][36];
  int b = blockIdx.x;
  int tr = b >> 5, tc = b & 31;
  int t = threadIdx.x;
  int i = t >> 3, j4 = (t & 7) << 2;
  const float4 v = *(const float4*)(src + (size_t)(tr * 32 + i) * 1024 + tc * 32 + j4);
  tile[i][j4 + 0] = f2bf(v.x);
  tile[i][j4 + 1] = f2bf(v.y);
  tile[i][j4 + 2] = f2bf(v.z);
  tile[i][j4 + 3] = f2bf(v.w);
  __syncthreads();
  int c = t >> 3, r4 = (t & 7) << 2;
  short4v o;
  o[0] = (short)tile[r4 + 0][c];
  o[1] = (short)tile[r4 + 1][c];
  o[2] = (short)tile[r4 + 2][c];
  o[3] = (short)tile[r4 + 3][c];
  *(short4v*)(dst + (size_t)(tc * 32 + c) * 1024 + tr * 32 + r4) = o;
}

// ---------------- xW GEMM: C[M,1024] = A[M,1024] @ B + bias, B given as B^T bf16 [N][K]
// 128x128 tile, 4 waves, BK=32, bf16 MFMA, fp32 output.
__global__ __launch_bounds__(256, 2) void xw_gemm(const float* __restrict__ A,
                                                  const unsigned short* __restrict__ BT,
                                                  const float* __restrict__ bias,
                                                  float* __restrict__ C) {
  __shared__ unsigned short As[128][40];  // 32 k + 8 pad
  __shared__ unsigned short Bs[128][40];  // rows = n, 32 k + 8 pad
  int b = blockIdx.x;
  int swz = (b & 7) * 256 + (b >> 3);  // XCD-contiguous chunks (2048 % 8 == 0)
  int tn = swz & 7, tm = swz >> 3;
  int t = threadIdx.x, lane = t & 63, wave = t >> 6;
  int l15 = lane & 15, l4 = lane >> 4;
  int wm = wave >> 1, wn = wave & 1;

  f32x4 acc[4][4];
#pragma unroll
  for (int i = 0; i < 4; ++i)
#pragma unroll
    for (int j = 0; j < 4; ++j) acc[i][j] = (f32x4){0.f, 0.f, 0.f, 0.f};

  int sm = t >> 1, sh = (t & 1) << 4;  // staging row / 16-elem half
  const float* a_src = A + (size_t)(tm * 128 + sm) * 1024 + sh;
  const unsigned short* b_src = BT + (size_t)(tn * 128 + sm) * 1024 + sh;

  for (int kt = 0; kt < 32; ++kt) {
    // stage A (fp32 -> bf16)
    float4 av0 = *(const float4*)(a_src + kt * 32 + 0);
    float4 av1 = *(const float4*)(a_src + kt * 32 + 4);
    float4 av2 = *(const float4*)(a_src + kt * 32 + 8);
    float4 av3 = *(const float4*)(a_src + kt * 32 + 12);
    short8 w0, w1;
    w0[0] = (short)f2bf(av0.x); w0[1] = (short)f2bf(av0.y);
    w0[2] = (short)f2bf(av0.z); w0[3] = (short)f2bf(av0.w);
    w0[4] = (short)f2bf(av1.x); w0[5] = (short)f2bf(av1.y);
    w0[6] = (short)f2bf(av1.z); w0[7] = (short)f2bf(av1.w);
    w1[0] = (short)f2bf(av2.x); w1[1] = (short)f2bf(av2.y);
    w1[2] = (short)f2bf(av2.z); w1[3] = (short)f2bf(av2.w);
    w1[4] = (short)f2bf(av3.x); w1[5] = (short)f2bf(av3.y);
    w1[6] = (short)f2bf(av3.z); w1[7] = (short)f2bf(av3.w);
    *(short8*)&As[sm][sh] = w0;
    *(short8*)&As[sm][sh + 8] = w1;
    // stage B (already bf16)
    short8 bv0 = *(const short8*)(b_src + kt * 32 + 0);
    short8 bv1 = *(const short8*)(b_src + kt * 32 + 8);
    *(short8*)&Bs[sm][sh] = bv0;
    *(short8*)&Bs[sm][sh + 8] = bv1;
    __syncthreads();

    short8 af[4], bfr[4];
#pragma unroll
    for (int i = 0; i < 4; ++i) af[i] = *(const short8*)&As[wm * 64 + i * 16 + l15][8 * l4];
#pragma unroll
    for (int j = 0; j < 4; ++j) bfr[j] = *(const short8*)&Bs[wn * 64 + j * 16 + l15][8 * l4];
#pragma unroll
    for (int i = 0; i < 4; ++i)
#pragma unroll
      for (int j = 0; j < 4; ++j)
        acc[i][j] = __builtin_amdgcn_mfma_f32_16x16x32_bf16(af[i], bfr[j], acc[i][j], 0, 0, 0);
    __syncthreads();
  }

#pragma unroll
  for (int i = 0; i < 4; ++i) {
    int row0 = tm * 128 + wm * 64 + i * 16 + l4 * 4;
#pragma unroll
    for (int j = 0; j < 4; ++j) {
      int col = tn * 128 + wn * 64 + j * 16 + l15;
      float bv = bias[col];
#pragma unroll
      for (int r = 0; r < 4; ++r)
        C[(size_t)(row0 + r) * 1024 + col] = acc[i][j][r] + bv;
    }
  }
}

// ---------------- persistent recurrent scan
// 256 WGs x 256 threads. WG -> (bg in 0..3, cg in 0..63); tile = batches [16*bg,+16) x cols [16*cg,+16).
// W_hh^T slice (16 cols x 1024 k, bf16) lives in LDS for all 512 steps.
// Per step: wave w accumulates K-range [256w, 256w+256) via 8 MFMAs; LDS reduce; all-wave epilogue;
// flag-array barrier per batch-group (agent-scope atomics + threadfence for cross-XCD visibility).
__global__ __launch_bounds__(256, 1) void rnn_scan(const unsigned short* __restrict__ whhT,
                                                   float* __restrict__ out,
                                                   unsigned short* __restrict__ hbuf,
                                                   int* __restrict__ flags) {
  int wg = blockIdx.x;
  int xcd = wg & 7;
  int bg = xcd >> 1;                        // 0..3 (clustered per XCD pair)
  int cg = ((wg >> 3) << 1) | (xcd & 1);    // 0..63
  int t = threadIdx.x, lane = t & 63, wave = t >> 6;
  int l15 = lane & 15, l4 = lane >> 4;

  __shared__ unsigned short wt[16][1032];          // 16 cols x 1024 k (+8 pad)
  __shared__ __align__(16) float red[4][64][4];    // per-wave partial accs

  {  // load this WG's W^T slice once
    int row = t >> 4, seg = t & 15;
    const unsigned short* src = whhT + (size_t)(cg * 16 + row) * 1024 + seg * 64;
    unsigned short* dstp = &wt[row][seg * 64];
#pragma unroll
    for (int j = 0; j < 8; ++j) *(short8*)(dstp + j * 8) = *(const short8*)(src + j * 8);
  }
  __syncthreads();

  for (int s = 0; s < T_STEPS; ++s) {
    f32x4 acc = (f32x4){0.f, 0.f, 0.f, 0.f};
    if (s > 0) {
      // wait for all 64 col-group flags of this batch-group to reach s (h_{s-1} ready)
      const int* fl = flags + bg * 64;
      for (;;) {
        int v = __hip_atomic_load(fl + lane, __ATOMIC_RELAXED, __HIP_MEMORY_SCOPE_AGENT);
        if (__all(v >= s)) break;
        __builtin_amdgcn_s_sleep(1);
      }
      __threadfence();  // acquire: invalidate stale cached h
      const unsigned short* hprev = hbuf + (size_t)((s - 1) & 1) * BATCH * HDIM;
      const unsigned short* arow = hprev + (size_t)(bg * 16 + l15) * HDIM + wave * 256 + 8 * l4;
      short8 a[8];
#pragma unroll
      for (int i = 0; i < 8; ++i) a[i] = *(const short8*)(arow + i * 32);
#pragma unroll
      for (int i = 0; i < 8; ++i) {
        short8 bfrag = *(const short8*)&wt[l15][wave * 256 + i * 32 + 8 * l4];
        acc = __builtin_amdgcn_mfma_f32_16x16x32_bf16(a[i], bfrag, acc, 0, 0, 0);
      }
    }
    *(f32x4*)&red[wave][lane][0] = acc;
    __syncthreads();
    // epilogue, wave-parallel over the 4 C-rows (r = wave)
    float sum = red[0][lane][wave] + red[1][lane][wave] + red[2][lane][wave] + red[3][lane][wave];
    int row = bg * 16 + l4 * 4 + wave;  // batch index
    int col = cg * 16 + l15;            // hidden index
    size_t oidx = ((size_t)s * BATCH + row) * HDIM + col;
    float hv = tanhf(out[oidx] + sum);
    out[oidx] = hv;
    hbuf[(size_t)(s & 1) * BATCH * HDIM + (size_t)row * HDIM + col] = f2bf(hv);
    if (s == T_STEPS - 1)
      out[(size_t)MROWS * HDIM + (size_t)row * HDIM + col] = hv;  // last_state
    __threadfence();   // release: flush h stores to coherence point
    __syncthreads();   // all waves' stores flushed before flag
    if (t == 0 && s != T_STEPS - 1)
      __hip_atomic_store(flags + bg * 64 + cg, s + 1, __ATOMIC_RELEASE, __HIP_MEMORY_SCOPE_AGENT);
  }
}

extern "C" void kernel_launch(void* const* d_in, const int* in_sizes, int n_in,
                              void* d_out, int out_size, void* d_ws, size_t ws_size,
                              hipStream_t stream) {
  const float* inp = (const float*)d_in[0];   // [512,64,1024] fp32
  const float* wxh = (const float*)d_in[1];   // [1024,1024]
  const float* whh = (const float*)d_in[2];   // [1024,1024]
  const float* bh  = (const float*)d_in[3];   // [1024]
  float* out = (float*)d_out;

  char* ws = (char*)d_ws;
  unsigned short* whhT = (unsigned short*)(ws);                         // 2 MB
  unsigned short* wxhT = (unsigned short*)(ws + (2u << 20));            // 2 MB
  unsigned short* hbuf = (unsigned short*)(ws + (4u << 20));            // 256 KB ping-pong
  int* flags = (int*)(ws + (4u << 20) + (1u << 19));                    // 1 KB

  hipMemsetAsync(flags, 0, 4096, stream);
  transpose_cvt<<<1024, 256, 0, stream>>>(whh, whhT);
  transpose_cvt<<<1024, 256, 0, stream>>>(wxh, wxhT);
  xw_gemm<<<2048, 256, 0, stream>>>(inp, wxhT, bh, out);
  rnn_scan<<<256, 256, 0, stream>>>(whhT, out, hbuf, flags);
}

// Round 2
// 2548.910 us; speedup vs baseline: 9.5283x; 9.5283x over previous
//
#include <hip/hip_runtime.h>
#include <hip/hip_bf16.h>
#include <stdint.h>

typedef __attribute__((ext_vector_type(8))) short short8;
typedef __attribute__((ext_vector_type(4))) short short4v;
typedef __attribute__((ext_vector_type(4))) float f32x4;

#define T_STEPS 512
#define BATCH 64
#define HDIM 1024
#define IDIM 1024
#define MROWS (T_STEPS * BATCH)  // 32768

__device__ __forceinline__ unsigned short f2bf(float f) {
  unsigned int u = __float_as_uint(f);
  u += 0x7FFFu + ((u >> 16) & 1u);  // RNE
  return (unsigned short)(u >> 16);
}

// ---------------- transpose + convert: dst[n][k] = bf16(src[k][n]), 1024x1024
__global__ __launch_bounds__(256) void transpose_cvt(const float* __restrict__ src,
                                                     unsigned short* __restrict__ dst) {
  __shared__ unsigned short tile[32][36];
  int b = blockIdx.x;
  int tr = b >> 5, tc = b & 31;
  int t = threadIdx.x;
  int i = t >> 3, j4 = (t & 7) << 2;
  const float4 v = *(const float4*)(src + (size_t)(tr * 32 + i) * 1024 + tc * 32 + j4);
  tile[i][j4 + 0] = f2bf(v.x);
  tile[i][j4 + 1] = f2bf(v.y);
  tile[i][j4 + 2] = f2bf(v.z);
  tile[i][j4 + 3] = f2bf(v.w);
  __syncthreads();
  int c = t >> 3, r4 = (t & 7) << 2;
  short4v o;
  o[0] = (short)tile[r4 + 0][c];
  o[1] = (short)tile[r4 + 1][c];
  o[2] = (short)tile[r4 + 2][c];
  o[3] = (short)tile[r4 + 3][c];
  *(short4v*)(dst + (size_t)(tc * 32 + c) * 1024 + tr * 32 + r4) = o;
}

// ---------------- xW GEMM: C[M,1024] = A[M,1024] @ B + bias, B given as B^T bf16 [N][K]
__global__ __launch_bounds__(256, 2) void xw_gemm(const float* __restrict__ A,
                                                  const unsigned short* __restrict__ BT,
                                                  const float* __restrict__ bias,
                                                  float* __restrict__ C) {
  __shared__ unsigned short As[128][40];
  __shared__ unsigned short Bs[128][40];
  int b = blockIdx.x;
  int swz = (b & 7) * 256 + (b >> 3);
  int tn = swz & 7, tm = swz >> 3;
  int t = threadIdx.x, lane = t & 63, wave = t >> 6;
  int l15 = lane & 15, l4 = lane >> 4;
  int wm = wave >> 1, wn = wave & 1;

  f32x4 acc[4][4];
#pragma unroll
  for (int i = 0; i < 4; ++i)
#pragma unroll
    for (int j = 0; j < 4; ++j) acc[i][j] = (f32x4){0.f, 0.f, 0.f, 0.f};

  int sm = t >> 1, sh = (t & 1) << 4;
  const float* a_src = A + (size_t)(tm * 128 + sm) * 1024 + sh;
  const unsigned short* b_src = BT + (size_t)(tn * 128 + sm) * 1024 + sh;

  for (int kt = 0; kt < 32; ++kt) {
    float4 av0 = *(const float4*)(a_src + kt * 32 + 0);
    float4 av1 = *(const float4*)(a_src + kt * 32 + 4);
    float4 av2 = *(const float4*)(a_src + kt * 32 + 8);
    float4 av3 = *(const float4*)(a_src + kt * 32 + 12);
    short8 w0, w1;
    w0[0] = (short)f2bf(av0.x); w0[1] = (short)f2bf(av0.y);
    w0[2] = (short)f2bf(av0.z); w0[3] = (short)f2bf(av0.w);
    w0[4] = (short)f2bf(av1.x); w0[5] = (short)f2bf(av1.y);
    w0[6] = (short)f2bf(av1.z); w0[7] = (short)f2bf(av1.w);
    w1[0] = (short)f2bf(av2.x); w1[1] = (short)f2bf(av2.y);
    w1[2] = (short)f2bf(av2.z); w1[3] = (short)f2bf(av2.w);
    w1[4] = (short)f2bf(av3.x); w1[5] = (short)f2bf(av3.y);
    w1[6] = (short)f2bf(av3.z); w1[7] = (short)f2bf(av3.w);
    *(short8*)&As[sm][sh] = w0;
    *(short8*)&As[sm][sh + 8] = w1;
    short8 bv0 = *(const short8*)(b_src + kt * 32 + 0);
    short8 bv1 = *(const short8*)(b_src + kt * 32 + 8);
    *(short8*)&Bs[sm][sh] = bv0;
    *(short8*)&Bs[sm][sh + 8] = bv1;
    __syncthreads();

    short8 af[4], bfr[4];
#pragma unroll
    for (int i = 0; i < 4; ++i) af[i] = *(const short8*)&As[wm * 64 + i * 16 + l15][8 * l4];
#pragma unroll
    for (int j = 0; j < 4; ++j) bfr[j] = *(const short8*)&Bs[wn * 64 + j * 16 + l15][8 * l4];
#pragma unroll
    for (int i = 0; i < 4; ++i)
#pragma unroll
      for (int j = 0; j < 4; ++j)
        acc[i][j] = __builtin_amdgcn_mfma_f32_16x16x32_bf16(af[i], bfr[j], acc[i][j], 0, 0, 0);
    __syncthreads();
  }

#pragma unroll
  for (int i = 0; i < 4; ++i) {
    int row0 = tm * 128 + wm * 64 + i * 16 + l4 * 4;
#pragma unroll
    for (int j = 0; j < 4; ++j) {
      int col = tn * 128 + wn * 64 + j * 16 + l15;
      float bv = bias[col];
#pragma unroll
      for (int r = 0; r < 4; ++r)
        C[(size_t)(row0 + r) * 1024 + col] = acc[i][j][r] + bv;
    }
  }
}

// ---------------- coherent (cross-XCD) access helpers: sc0 sc1 bypasses the
// non-coherent per-XCD L1/L2 and hits the device coherence point directly.
// NO buffer_wbl2 / buffer_inv cache maintenance anywhere.
__device__ __forceinline__ void coh_store_short(unsigned short* p, unsigned int v) {
  asm volatile("global_store_short %0, %1, off sc0 sc1" ::"v"(p), "v"(v) : "memory");
}
__device__ __forceinline__ void coh_store_dword(int* p, int v) {
  asm volatile("global_store_dword %0, %1, off sc0 sc1" ::"v"(p), "v"(v) : "memory");
}
__device__ __forceinline__ int coh_load_dword(const int* p) {
  int r;
  asm volatile("global_load_dword %0, %1, off sc0 sc1\n\ts_waitcnt vmcnt(0)"
               : "=v"(r) : "v"(p) : "memory");
  return r;
}
__device__ __forceinline__ void coh_load_b128_issue(short8* dst, const unsigned short* p) {
  asm volatile("global_load_dwordx4 %0, %1, off sc0 sc1" : "=v"(*dst) : "v"(p) : "memory");
}

// ---------------- persistent recurrent scan (fence-free producer/consumer)
__global__ __launch_bounds__(256, 1) void rnn_scan(const unsigned short* __restrict__ whhT,
                                                   float* __restrict__ out,
                                                   unsigned short* __restrict__ hbuf,
                                                   int* __restrict__ flags) {
  int wg = blockIdx.x;
  int xcd = wg & 7;
  int bg = xcd >> 1;                        // 0..3
  int cg = ((wg >> 3) << 1) | (xcd & 1);    // 0..63
  int t = threadIdx.x, lane = t & 63, wave = t >> 6;
  int l15 = lane & 15, l4 = lane >> 4;

  __shared__ unsigned short wt[16][1032];          // 16 cols x 1024 k (+8 pad)
  __shared__ __align__(16) float red[4][64][4];

  {  // park this WG's W_hh^T slice in LDS for all 512 steps
    int row = t >> 4, seg = t & 15;
    const unsigned short* src = whhT + (size_t)(cg * 16 + row) * 1024 + seg * 64;
    unsigned short* dstp = &wt[row][seg * 64];
#pragma unroll
    for (int j = 0; j < 8; ++j) *(short8*)(dstp + j * 8) = *(const short8*)(src + j * 8);
  }
  __syncthreads();

  const int* fl = flags + bg * 64 + lane;

  for (int s = 0; s < T_STEPS; ++s) {
    f32x4 acc = (f32x4){0.f, 0.f, 0.f, 0.f};
    if (s > 0) {
      // acquire: poll the 64 col-group flags of this batch-group (coherent loads)
      for (;;) {
        int v = coh_load_dword(fl);
        if (__all(v >= s)) break;
        __builtin_amdgcn_s_sleep(1);
      }
      // coherent h_{s-1} loads (bypass stale L1/L2 — no invalidate needed)
      const unsigned short* hprev = hbuf + (size_t)((s - 1) & 1) * BATCH * HDIM;
      const unsigned short* arow = hprev + (size_t)(bg * 16 + l15) * HDIM + wave * 256 + 8 * l4;
      short8 a[8];
#pragma unroll
      for (int i = 0; i < 8; ++i) coh_load_b128_issue(&a[i], arow + i * 32);
      asm volatile("s_waitcnt vmcnt(0)" ::: "memory");
      __builtin_amdgcn_sched_barrier(0);
#pragma unroll
      for (int i = 0; i < 8; ++i) {
        short8 bfrag = *(const short8*)&wt[l15][wave * 256 + i * 32 + 8 * l4];
        acc = __builtin_amdgcn_mfma_f32_16x16x32_bf16(a[i], bfrag, acc, 0, 0, 0);
      }
    }
    *(f32x4*)&red[wave][lane][0] = acc;
    __syncthreads();
    float sum = red[0][lane][wave] + red[1][lane][wave] + red[2][lane][wave] + red[3][lane][wave];
    int row = bg * 16 + l4 * 4 + wave;  // batch index
    int col = cg * 16 + l15;            // hidden index
    size_t oidx = ((size_t)s * BATCH + row) * HDIM + col;
    float hv = tanhf(out[oidx] + sum);
    out[oidx] = hv;  // normal cached store (element private to this thread)
    // coherent write-through h store
    coh_store_short(hbuf + (size_t)(s & 1) * BATCH * HDIM + (size_t)row * HDIM + col,
                    (unsigned int)f2bf(hv));
    if (s == T_STEPS - 1)
      out[(size_t)MROWS * HDIM + (size_t)row * HDIM + col] = hv;  // last_state
    // release: drain the write-through stores, then (one lane) publish the flag
    asm volatile("s_waitcnt vmcnt(0)" ::: "memory");
    __syncthreads();
    if (t == 0 && s != T_STEPS - 1)
      coh_store_dword(flags + bg * 64 + cg, s + 1);
  }
}

extern "C" void kernel_launch(void* const* d_in, const int* in_sizes, int n_in,
                              void* d_out, int out_size, void* d_ws, size_t ws_size,
                              hipStream_t stream) {
  const float* inp = (const float*)d_in[0];   // [512,64,1024] fp32
  const float* wxh = (const float*)d_in[1];   // [1024,1024]
  const float* whh = (const float*)d_in[2];   // [1024,1024]
  const float* bh  = (const float*)d_in[3];   // [1024]
  float* out = (float*)d_out;

  char* ws = (char*)d_ws;
  unsigned short* whhT = (unsigned short*)(ws);                 // 2 MB
  unsigned short* wxhT = (unsigned short*)(ws + (2u << 20));    // 2 MB
  unsigned short* hbuf = (unsigned short*)(ws + (4u << 20));    // 256 KB ping-pong
  int* flags = (int*)(ws + (4u << 20) + (1u << 19));            // 1 KB

  hipMemsetAsync(flags, 0, 4096, stream);
  transpose_cvt<<<1024, 256, 0, stream>>>(whh, whhT);
  transpose_cvt<<<1024, 256, 0, stream>>>(wxh, wxhT);
  xw_gemm<<<2048, 256, 0, stream>>>(inp, wxhT, bh, out);
  rnn_scan<<<256, 256, 0, stream>>>(whhT, out, hbuf, flags);
}